// Round 1
// baseline (130.580 us; speedup 1.0000x reference)
//
#include <hip/hip_runtime.h>
#include <stdint.h>

#define N_ROWS   16384
#define IN_DIM   512
#define CB_DIM   16
#define CB_VOCAB 8192

// ---- K1 geometry
#define PROJ_BLOCKS 512                          // 32 rows each, full K
#define PREP_BLOCKS 128                          // 4 code-tiles each

// ---- scan geometry
#define N_RT   (N_ROWS / 16)                     // 1024 row-tiles
#define N_CT   (CB_VOCAB / 16)                   // 512 code-tiles
#define CODEPARTS 16
#define CT_PER_PART (N_CT / CODEPARTS)           // 32
#define N_ROWGRP 64                              // 256 rows per rowgrp
#define GRP    8                                 // code-tiles per LDS stage group
#define NGRP   (CT_PER_PART / GRP)               // 4 groups

// ---- workspace layout (bytes), ~3.2 MB
#define WS_OFF_AFA  0                            // A-frag [A1|A2]: 1 MB
#define WS_OFF_AFB  (1u << 20)                   // A-frag [A1|A3]: 1 MB
#define WS_OFF_BHH  (2u << 20)                   // B-frag [B1;B2]: 512 KB
#define WS_OFF_B31  ((2u << 20) + (512u << 10))  // B-frag [B3;B1]: 512 KB
#define WS_OFF_PART (3u << 20)                   // u64[16384]: 128 KB
#define WS_OFF_CNT  ((3u << 20) + (128u << 10))  // u32[64]

typedef __attribute__((ext_vector_type(8))) short bf16x8;
typedef __attribute__((ext_vector_type(4))) float f32x4;

// monotone float -> uint32 key (order-preserving)
__device__ __forceinline__ unsigned fkey(float f) {
    unsigned u = __float_as_uint(f);
    return (u & 0x80000000u) ? ~u : (u | 0x80000000u);
}

// fp32 -> bf16 bits, round-to-nearest-even
__device__ __forceinline__ unsigned short f2bf(float f) {
    unsigned u = __float_as_uint(f);
    return (unsigned short)((u + 0x7FFFu + ((u >> 16) & 1u)) >> 16);
}
__device__ __forceinline__ float bf2f(unsigned short h) {
    return __uint_as_float(((unsigned)h) << 16);
}

// ---------------- K1: proj + fold + A-frag (blocks 0..511); CB prep + init
// (blocks 512..639).
// proj: block = 32 rows x full K=512. Wave w, lane-half h cover k in
// [128w+64h, +64); lane owns 1 row. 8 k-partials in LDS, folded in-block,
// 3-way bf16 split, A-frags written directly (no xp roundtrip).
__global__ __launch_bounds__(256, 2)
void k_front(const float* __restrict__ x, const float* __restrict__ P,
             const float* __restrict__ CB,
             bf16x8* __restrict__ AfragA, bf16x8* __restrict__ AfragB,
             bf16x8* __restrict__ Bhh, bf16x8* __restrict__ B31,
             unsigned long long* __restrict__ part, unsigned* __restrict__ cnt) {
    __shared__ float4 Ps[IN_DIM * 4];            // P [512][16]: 32 KB
    __shared__ float  accs[8][32][20];           // 8 k-partials x 32 rows: 20 KB

    const int wave = threadIdx.x >> 6;
    const int lane = threadIdx.x & 63;

    if (blockIdx.x >= PROJ_BLOCKS) {
        // ---- prep path: zero part/cnt, build CB B-frags ----
        const int pb = blockIdx.x - PROJ_BLOCKS;
        if (threadIdx.x < 128) part[pb * 128 + threadIdx.x] = 0ull;
        if (pb == 0 && threadIdx.x < 64) cnt[threadIdx.x] = 0u;

        const int ct   = pb * 4 + wave;
        const int n    = lane & 15;
        const int quad = lane >> 4;
        const int kh   = (quad & 1) * 8;
        const int lvl  = quad >> 1;
        const int code = ct * 16 + n;

        const float4* b4 = (const float4*)(CB + (size_t)code * CB_DIM + kh);
        float4 a = b4[0], b = b4[1];
        float v[8] = {a.x, a.y, a.z, a.w, b.x, b.y, b.z, b.w};

        bf16x8 shh, s31;
#pragma unroll
        for (int j = 0; j < 8; ++j) {
            float f = v[j];
            unsigned short b1 = f2bf(f);  float r1 = f - bf2f(b1);
            unsigned short b2 = f2bf(r1); float r2 = r1 - bf2f(b2);
            unsigned short b3 = f2bf(r2);
            shh[j] = (short)(lvl ? b2 : b1);
            s31[j] = (short)(lvl ? b1 : b3);
        }
        Bhh[(size_t)ct * 64 + lane] = shh;
        B31[(size_t)ct * 64 + lane] = s31;
        return;
    }

    // ---- proj path ----
    const int b = blockIdx.x;
    for (int i = threadIdx.x; i < IN_DIM * 4; i += 256)
        Ps[i] = ((const float4*)P)[i];
    __syncthreads();

    const int r32   = lane & 31;
    const int khalf = lane >> 5;
    const int row   = b * 32 + r32;
    const int kb    = 128 * wave + 64 * khalf;   // this lane's absolute k base

    float acc[16];
#pragma unroll
    for (int c = 0; c < 16; ++c) acc[c] = 0.0f;

    const float4* xr = (const float4*)(x + (size_t)row * IN_DIM + kb);

#pragma unroll 4
    for (int i = 0; i < 16; ++i) {               // 16 float4s = 64 k's
        float4 xv = xr[i];
        float xs[4] = {xv.x, xv.y, xv.z, xv.w};
#pragma unroll
        for (int kk = 0; kk < 4; ++kk) {
#pragma unroll
            for (int q = 0; q < 4; ++q) {
                float4 pv = Ps[(kb + 4 * i + kk) * 4 + q];
                acc[4 * q + 0] += xs[kk] * pv.x;
                acc[4 * q + 1] += xs[kk] * pv.y;
                acc[4 * q + 2] += xs[kk] * pv.z;
                acc[4 * q + 3] += xs[kk] * pv.w;
            }
        }
    }

    const int pslot = wave * 2 + khalf;
#pragma unroll
    for (int c = 0; c < 16; ++c) accs[pslot][r32][c] = acc[c];
    __syncthreads();

    // fold 8 partials + 3-way split + emit A-frags (2 row-tiles per block)
    if (threadIdx.x < 128) {
        const int rtl  = threadIdx.x >> 6;       // 0/1
        const int l2   = threadIdx.x & 63;
        const int m    = l2 & 15;
        const int quad = l2 >> 4;
        const int kh   = (quad & 1) * 8;
        const int lvl  = quad >> 1;
        const int rloc = rtl * 16 + m;

        float v[8];
#pragma unroll
        for (int j = 0; j < 8; ++j) v[j] = 0.0f;
#pragma unroll
        for (int p = 0; p < 8; ++p) {
#pragma unroll
            for (int j = 0; j < 8; ++j) v[j] += accs[p][rloc][kh + j];
        }

        bf16x8 sa, sb;
#pragma unroll
        for (int j = 0; j < 8; ++j) {
            float f = v[j];
            unsigned short b1 = f2bf(f);  float r1 = f - bf2f(b1);
            unsigned short b2 = f2bf(r1); float r2 = r1 - bf2f(b2);
            unsigned short b3 = f2bf(r2);
            sa[j] = (short)(lvl ? b2 : b1);
            sb[j] = (short)(lvl ? b3 : b1);
        }
        AfragA[(size_t)(2 * b + rtl) * 64 + l2] = sa;
        AfragB[(size_t)(2 * b + rtl) * 64 + l2] = sb;
    }
}

// ---------------- K2: MFMA sim + argmax + last-block finalize ---------------
// grid 1024 = 64 rowgrps x 16 codeparts; wave = 4 row-tiles x 32 code-tiles.
// B-frags are now staged block-wide into LDS (double-buffered 8-ct groups,
// T14 async split: issue next group's global loads BEFORE processing the
// current group, ds_write + one barrier per group). This cuts the former 6x
// per-wave global re-read (393 MB of L2 traffic kernel-wide -> 66 MB); the
// lane^32 swapped operand becomes a free second LDS read. k_scan should move
// from L2-BW-bound (~11 us) to the VALU argmax floor (~5-6 us).
// 3 chained bf16 MFMAs per tile (fp32-accurate 3-way split). Cross-block
// argmax via device-scope atomicMax(u64); the 16th block to finish a rowgrp
// decodes part[] -> out[] (no extra dispatch).
__global__ __launch_bounds__(256, 4)
void k_scan(const bf16x8* __restrict__ AfragA, const bf16x8* __restrict__ AfragB,
            const bf16x8* __restrict__ Bhh, const bf16x8* __restrict__ B31,
            unsigned long long* __restrict__ part, unsigned* __restrict__ cnt,
            int* __restrict__ out) {
    __shared__ bf16x8 Bs[2][2][GRP][64];         // [buf][hh/31][ct][lane]: 32 KB
    __shared__ int s_done;
    const int codepart = blockIdx.x & (CODEPARTS - 1);
    const int rowgrp   = blockIdx.x >> 4;
    const int wave     = threadIdx.x >> 6;
    const int lane     = threadIdx.x & 63;
    const int n        = lane & 15;
    const int quad     = lane >> 4;
    const int rt_base  = rowgrp * 16 + wave * 4;

    bf16x8 Aa[4], Ab[4];
#pragma unroll
    for (int t = 0; t < 4; ++t) {
        Aa[t] = AfragA[(size_t)(rt_base + t) * 64 + lane];
        Ab[t] = AfragB[(size_t)(rt_base + t) * 64 + lane];
    }

    float bestv[4][4];
    int   bestc[4][4];
#pragma unroll
    for (int t = 0; t < 4; ++t)
#pragma unroll
        for (int r = 0; r < 4; ++r) { bestv[t][r] = -INFINITY; bestc[t][r] = 0; }

    const int ct0 = codepart * CT_PER_PART;
    const int ctl = wave * 2;                    // this wave's 2 stage rows

    // prologue: stage group 0 into Bs[0]
    {
        size_t cb = (size_t)(ct0 + ctl) * 64 + lane;
        bf16x8 p0 = Bhh[cb], p1 = Bhh[cb + 64];
        bf16x8 p2 = B31[cb], p3 = B31[cb + 64];
        Bs[0][0][ctl][lane] = p0;  Bs[0][0][ctl + 1][lane] = p1;
        Bs[0][1][ctl][lane] = p2;  Bs[0][1][ctl + 1][lane] = p3;
    }
    __syncthreads();

    for (int g = 0; g < NGRP; ++g) {
        const int bi = g & 1;

        // issue next group's global loads now; they complete during compute
        bf16x8 st0, st1, st2, st3;
        if (g + 1 < NGRP) {
            size_t cb = (size_t)(ct0 + (g + 1) * GRP + ctl) * 64 + lane;
            st0 = Bhh[cb];  st1 = Bhh[cb + 64];
            st2 = B31[cb];  st3 = B31[cb + 64];
        }

#pragma unroll
        for (int cc = 0; cc < GRP; ++cc) {
            bf16x8 b1  = Bs[bi][0][cc][lane];
            bf16x8 b1s = Bs[bi][0][cc][lane ^ 32];
            bf16x8 b3  = Bs[bi][1][cc][lane];
            const int c = g * GRP + cc;
#pragma unroll
            for (int t = 0; t < 4; ++t) {
                f32x4 s = __builtin_amdgcn_mfma_f32_16x16x32_bf16(
                              Aa[t], b1, (f32x4){0.f, 0.f, 0.f, 0.f}, 0, 0, 0);
                s = __builtin_amdgcn_mfma_f32_16x16x32_bf16(Aa[t], b1s, s, 0, 0, 0);
                s = __builtin_amdgcn_mfma_f32_16x16x32_bf16(Ab[t], b3,  s, 0, 0, 0);
#pragma unroll
                for (int r = 0; r < 4; ++r) {
                    if (s[r] > bestv[t][r]) { bestv[t][r] = s[r]; bestc[t][r] = c; }
                }
            }
        }

        // write-late half of the async stage, then one barrier per group.
        // safe: buffer bi^1 was last read in group g-1, before g-1's barrier.
        if (g + 1 < NGRP) {
            const int nbi = bi ^ 1;
            Bs[nbi][0][ctl][lane] = st0;  Bs[nbi][0][ctl + 1][lane] = st1;
            Bs[nbi][1][ctl][lane] = st2;  Bs[nbi][1][ctl + 1][lane] = st3;
        }
        __syncthreads();
    }

    // reduce over the 16 code-class lanes, then device-scope max per row
#pragma unroll
    for (int t = 0; t < 4; ++t) {
#pragma unroll
        for (int r = 0; r < 4; ++r) {
            unsigned code = (unsigned)(codepart * 512 + bestc[t][r] * 16 + n);
            unsigned long long packed =
                ((unsigned long long)fkey(bestv[t][r]) << 32) |
                (unsigned long long)(0xFFFFFFFFu - code);
#pragma unroll
            for (int mk = 1; mk <= 8; mk <<= 1) {
                unsigned long long o = __shfl_xor(packed, mk, 64);
                packed = (o > packed) ? o : packed;
            }
            if (n == 0) {
                int row = (rt_base + t) * 16 + quad * 4 + r;
                atomicMax(&part[row], packed);
            }
        }
    }

    // __syncthreads drains vmcnt -> all this block's atomics are complete
    __syncthreads();
    if (threadIdx.x == 0)
        s_done = (atomicAdd(&cnt[rowgrp], 1u) == (unsigned)(CODEPARTS - 1));
    __syncthreads();

    if (s_done) {
        int row = rowgrp * 256 + threadIdx.x;
        unsigned long long v = atomicAdd(&part[row], 0ull);   // coherent read
        out[row] = (int)(0xFFFFFFFFu - (unsigned)(v & 0xFFFFFFFFull));
    }
}

extern "C" void kernel_launch(void* const* d_in, const int* in_sizes, int n_in,
                              void* d_out, int out_size, void* d_ws, size_t ws_size,
                              hipStream_t stream) {
    const float* x  = (const float*)d_in[0];   // [16384, 512]
    const float* P  = (const float*)d_in[1];   // [512, 16]
    const float* CB = (const float*)d_in[2];   // [8192, 16]
    int* out = (int*)d_out;                    // [16384] int32

    char* ws = (char*)d_ws;
    bf16x8* AfragA = (bf16x8*)(ws + WS_OFF_AFA);
    bf16x8* AfragB = (bf16x8*)(ws + WS_OFF_AFB);
    bf16x8* Bhh    = (bf16x8*)(ws + WS_OFF_BHH);
    bf16x8* B31    = (bf16x8*)(ws + WS_OFF_B31);
    unsigned long long* part = (unsigned long long*)(ws + WS_OFF_PART);
    unsigned* cnt  = (unsigned*)(ws + WS_OFF_CNT);

    k_front<<<PROJ_BLOCKS + PREP_BLOCKS, 256, 0, stream>>>(
        x, P, CB, AfragA, AfragB, Bhh, B31, part, cnt);            // 640 blocks
    k_scan<<<N_ROWGRP * CODEPARTS, 256, 0, stream>>>(
        AfragA, AfragB, Bhh, B31, part, cnt, out);                 // 1024 blocks
}